// Round 3
// baseline (209.888 us; speedup 1.0000x reference)
//
#include <hip/hip_runtime.h>

#define BATCH 32
#define NX 512
#define NY 512
#define XY (NX * NY)

__global__ __launch_bounds__(256) void psi11t_kernel(
    const float* __restrict__ s,
    const float* __restrict__ t,
    const float* __restrict__ c0,
    float* __restrict__ out)
{
    const int tid  = threadIdx.x;
    const int yg   = tid & 127;          // 128 y-groups of 4 per row
    const int xr   = tid >> 7;           // 0/1: row within the block's pair
    const int y0   = yg * 4;
    const int x    = blockIdx.x * 2 + xr;
    const int bidx = blockIdx.y;

    const int xm1 = (x + NX - 1) & (NX - 1);
    const int xp1 = (x + 1)      & (NX - 1);
    const int xm2 = (x + NX - 2) & (NX - 1);
    const int xp2 = (x + 2)      & (NX - 1);
    const int om4 = (y0 + NY - 4) & (NY - 1);
    const int op4 = (y0 + 4)      & (NY - 1);

    const float* sb = s + (size_t)bidx * 3 * XY;

    // windows: logical index w <-> y = y0 - 4 + w
    float cm[3][12], um[3][12], dm[3][12], u2[3][4], d2[3][4];

    #pragma unroll
    for (int c = 0; c < 3; ++c) {
        const float* base = sb + (size_t)c * XY;
        const float* rc  = base + (size_t)x   * NY;
        const float* rm  = base + (size_t)xm1 * NY;
        const float* rp  = base + (size_t)xp1 * NY;
        const float* rm2 = base + (size_t)xm2 * NY;
        const float* rp2 = base + (size_t)xp2 * NY;

        *(float4*)&cm[c][0] = *(const float4*)(rc + om4);
        *(float4*)&cm[c][4] = *(const float4*)(rc + y0);
        *(float4*)&cm[c][8] = *(const float4*)(rc + op4);
        *(float4*)&um[c][0] = *(const float4*)(rm + om4);
        *(float4*)&um[c][4] = *(const float4*)(rm + y0);
        *(float4*)&um[c][8] = *(const float4*)(rm + op4);
        *(float4*)&dm[c][0] = *(const float4*)(rp + om4);
        *(float4*)&dm[c][4] = *(const float4*)(rp + y0);
        *(float4*)&dm[c][8] = *(const float4*)(rp + op4);
        *(float4*)&u2[c][0] = *(const float4*)(rm2 + y0);
        *(float4*)&d2[c][0] = *(const float4*)(rp2 + y0);
    }

    const float coeff = 2.0f * t[0] * c0[0];

    float o[3][4];
    #pragma unroll
    for (int i = 0; i < 4; ++i) {
        float sc[3], sA[3], sB[3], sC[3], sD[3], Fs[3];
        float bc = 0.f, bA = 0.f, bB = 0.f, bC = 0.f, bD = 0.f;
        #pragma unroll
        for (int c = 0; c < 3; ++c) {
            sc[c] = cm[c][4 + i];
            sC[c] = cm[c][3 + i];        // y-1
            sD[c] = cm[c][5 + i];        // y+1
            float sCC = cm[c][2 + i];    // y-2
            float sDD = cm[c][6 + i];    // y+2
            sA[c] = um[c][4 + i];        // x-1
            float sAC = um[c][3 + i];
            float sAD = um[c][5 + i];
            sB[c] = dm[c][4 + i];        // x+1
            float sBC = dm[c][3 + i];
            float sBD = dm[c][5 + i];
            float sAA = u2[c][i];        // x-2
            float sBB = d2[c][i];        // x+2

            float nsum = sA[c] + sB[c] + sC[c] + sD[c];
            Fs[c] = nsum;
            bc += sc[c] * nsum;
            bA += sA[c] * (sAA + sc[c] + sAC + sAD);
            bB += sB[c] * (sc[c] + sBB + sBC + sBD);
            bC += sC[c] * (sAC + sBC + sCC + sc[c]);
            bD += sD[c] * (sAD + sBD + sc[c] + sDD);
        }
        float G[3];
        #pragma unroll
        for (int c = 0; c < 3; ++c)
            G[c] = Fs[c] * bc + sA[c] * bA + sB[c] * bB + sC[c] * bC + sD[c] * bD;
        o[0][i] = (sc[1] * G[2] - sc[2] * G[1]) * coeff;
        o[1][i] = (sc[2] * G[0] - sc[0] * G[2]) * coeff;
        o[2][i] = (sc[0] * G[1] - sc[1] * G[0]) * coeff;
    }

    float* ob = out + (size_t)bidx * 3 * XY + (size_t)x * NY + y0;
    *(float4*)(ob)          = make_float4(o[0][0], o[0][1], o[0][2], o[0][3]);
    *(float4*)(ob + XY)     = make_float4(o[1][0], o[1][1], o[1][2], o[1][3]);
    *(float4*)(ob + 2 * XY) = make_float4(o[2][0], o[2][1], o[2][2], o[2][3]);
}

extern "C" void kernel_launch(void* const* d_in, const int* in_sizes, int n_in,
                              void* d_out, int out_size, void* d_ws, size_t ws_size,
                              hipStream_t stream) {
    const float* s  = (const float*)d_in[0];
    const float* t  = (const float*)d_in[1];
    const float* c0 = (const float*)d_in[2];
    float* out = (float*)d_out;

    dim3 grid(NX / 2, BATCH);    // 256 x 32 = 8192 blocks, 2 rows/block
    psi11t_kernel<<<grid, 256, 0, stream>>>(s, t, c0, out);
}

// Round 5
// 209.049 us; speedup vs baseline: 1.0040x; 1.0040x over previous
//
#include <hip/hip_runtime.h>

#define BATCH 32
#define NX 512
#define NY 512
#define XY (NX * NY)

typedef float floatx4 __attribute__((ext_vector_type(4)));

__global__ __launch_bounds__(256) void psi11t_kernel(
    const float* __restrict__ s,
    const float* __restrict__ t,
    const float* __restrict__ c0,
    float* __restrict__ out)
{
    // XCD-aware swizzle: dispatch id D -> logical block L so each XCD (D%8)
    // owns 1024 CONSECUTIVE logical strips (4 full batches) -> x-halo rows
    // hit that XCD's L2 instead of re-fetching from HBM/L3.
    const int D = blockIdx.x;                 // 8192 blocks
    const int L = (D & 7) * 1024 + (D >> 3);
    const int bidx  = L >> 8;                 // 32 batches
    const int strip = L & 255;                // 256 strips of 2 rows

    const int tid = threadIdx.x;
    const int yg  = tid & 127;                // 128 y-groups of 4 per row
    const int xr  = tid >> 7;                 // 0/1: row within the pair
    const int y0  = yg * 4;
    const int x   = strip * 2 + xr;

    const int xm1 = (x + NX - 1) & (NX - 1);
    const int xp1 = (x + 1)      & (NX - 1);
    const int xm2 = (x + NX - 2) & (NX - 1);
    const int xp2 = (x + 2)      & (NX - 1);
    const int om4 = (y0 + NY - 4) & (NY - 1);
    const int op4 = (y0 + 4)      & (NY - 1);

    const float* sb = s + (size_t)bidx * 3 * XY;

    // windows: logical index w <-> y = y0 - 4 + w
    float cm[3][12], um[3][12], dm[3][12], u2[3][4], d2[3][4];

    #pragma unroll
    for (int c = 0; c < 3; ++c) {
        const float* base = sb + (size_t)c * XY;
        const float* rc  = base + (size_t)x   * NY;
        const float* rm  = base + (size_t)xm1 * NY;
        const float* rp  = base + (size_t)xp1 * NY;
        const float* rm2 = base + (size_t)xm2 * NY;
        const float* rp2 = base + (size_t)xp2 * NY;

        *(floatx4*)&cm[c][0] = *(const floatx4*)(rc + om4);
        *(floatx4*)&cm[c][4] = *(const floatx4*)(rc + y0);
        *(floatx4*)&cm[c][8] = *(const floatx4*)(rc + op4);
        *(floatx4*)&um[c][0] = *(const floatx4*)(rm + om4);
        *(floatx4*)&um[c][4] = *(const floatx4*)(rm + y0);
        *(floatx4*)&um[c][8] = *(const floatx4*)(rm + op4);
        *(floatx4*)&dm[c][0] = *(const floatx4*)(rp + om4);
        *(floatx4*)&dm[c][4] = *(const floatx4*)(rp + y0);
        *(floatx4*)&dm[c][8] = *(const floatx4*)(rp + op4);
        *(floatx4*)&u2[c][0] = *(const floatx4*)(rm2 + y0);
        *(floatx4*)&d2[c][0] = *(const floatx4*)(rp2 + y0);
    }

    const float coeff = 2.0f * t[0] * c0[0];

    float o[3][4];
    #pragma unroll
    for (int i = 0; i < 4; ++i) {
        float sc[3], sA[3], sB[3], sC[3], sD[3], Fs[3];
        float bc = 0.f, bA = 0.f, bB = 0.f, bC = 0.f, bD = 0.f;
        #pragma unroll
        for (int c = 0; c < 3; ++c) {
            sc[c] = cm[c][4 + i];
            sC[c] = cm[c][3 + i];        // y-1
            sD[c] = cm[c][5 + i];        // y+1
            float sCC = cm[c][2 + i];    // y-2
            float sDD = cm[c][6 + i];    // y+2
            sA[c] = um[c][4 + i];        // x-1
            float sAC = um[c][3 + i];
            float sAD = um[c][5 + i];
            sB[c] = dm[c][4 + i];        // x+1
            float sBC = dm[c][3 + i];
            float sBD = dm[c][5 + i];
            float sAA = u2[c][i];        // x-2
            float sBB = d2[c][i];        // x+2

            float nsum = sA[c] + sB[c] + sC[c] + sD[c];
            Fs[c] = nsum;
            bc += sc[c] * nsum;
            bA += sA[c] * (sAA + sc[c] + sAC + sAD);
            bB += sB[c] * (sc[c] + sBB + sBC + sBD);
            bC += sC[c] * (sAC + sBC + sCC + sc[c]);
            bD += sD[c] * (sAD + sBD + sc[c] + sDD);
        }
        float G[3];
        #pragma unroll
        for (int c = 0; c < 3; ++c)
            G[c] = Fs[c] * bc + sA[c] * bA + sB[c] * bB + sC[c] * bC + sD[c] * bD;
        o[0][i] = (sc[1] * G[2] - sc[2] * G[1]) * coeff;
        o[1][i] = (sc[2] * G[0] - sc[0] * G[2]) * coeff;
        o[2][i] = (sc[0] * G[1] - sc[1] * G[0]) * coeff;
    }

    float* ob = out + (size_t)bidx * 3 * XY + (size_t)x * NY + y0;
    floatx4 v0 = { o[0][0], o[0][1], o[0][2], o[0][3] };
    floatx4 v1 = { o[1][0], o[1][1], o[1][2], o[1][3] };
    floatx4 v2 = { o[2][0], o[2][1], o[2][2], o[2][3] };
    __builtin_nontemporal_store(v0, (floatx4*)(ob));
    __builtin_nontemporal_store(v1, (floatx4*)(ob + XY));
    __builtin_nontemporal_store(v2, (floatx4*)(ob + 2 * XY));
}

extern "C" void kernel_launch(void* const* d_in, const int* in_sizes, int n_in,
                              void* d_out, int out_size, void* d_ws, size_t ws_size,
                              hipStream_t stream) {
    const float* s  = (const float*)d_in[0];
    const float* t  = (const float*)d_in[1];
    const float* c0 = (const float*)d_in[2];
    float* out = (float*)d_out;

    psi11t_kernel<<<8192, 256, 0, stream>>>(s, t, c0, out);
}

// Round 6
// 193.760 us; speedup vs baseline: 1.0832x; 1.0789x over previous
//
#include <hip/hip_runtime.h>

#define BATCH 32
#define NX 512
#define NY 512
#define XY (NX * NY)

typedef float floatx4 __attribute__((ext_vector_type(4)));

__global__ __launch_bounds__(256) void psi11t_kernel(
    const float* __restrict__ s,
    const float* __restrict__ t,
    const float* __restrict__ c0,
    float* __restrict__ out)
{
    // XCD swizzle: each XCD (D%8) gets 512 consecutive logical blocks = 4 whole
    // batches -> all halo reuse (incl. x-wrap) stays within one XCD's L2.
    const int D = blockIdx.x;                 // 4096 blocks
    const int L = (D & 7) * 512 + (D >> 3);
    const int bidx  = L >> 7;                 // 32 batches
    const int strip = L & 127;                // 128 strips of 4 rows

    const int tid = threadIdx.x;
    const int yg  = tid & 127;                // 128 y-groups of 4
    const int xr  = tid >> 7;                 // 0/1: which row-pair
    const int y0  = yg * 4;
    const int x   = strip * 4 + xr * 2;       // outputs at rows x, x+1 (x even)

    const int xm2 = (x + NX - 2) & (NX - 1);
    const int xm1 = (x + NX - 1) & (NX - 1);
    const int xp1 = x + 1;                    // x even, <= 510 -> no wrap
    const int xp2 = (x + 2) & (NX - 1);
    const int xp3 = (x + 3) & (NX - 1);
    const int om4 = (y0 + NY - 4) & (NY - 1);
    const int op4 = (y0 + 4)      & (NY - 1);

    const float* sb = s + (size_t)bidx * 3 * XY;

    // Row windows. Index w <-> y = y0 - 4 + w (12-wide rows); A2m/B2p start at y0.
    float A2m[3][4], Am[3][12], C0[3][12], C1[3][12], Bp[3][12], B2p[3][4];

    #pragma unroll
    for (int c = 0; c < 3; ++c) {
        const float* base = sb + (size_t)c * XY;
        const float* rm2 = base + (size_t)xm2 * NY;
        const float* rm1 = base + (size_t)xm1 * NY;
        const float* r0  = base + (size_t)x   * NY;
        const float* r1  = base + (size_t)xp1 * NY;
        const float* rp2 = base + (size_t)xp2 * NY;
        const float* rp3 = base + (size_t)xp3 * NY;

        *(floatx4*)&A2m[c][0] = *(const floatx4*)(rm2 + y0);
        *(floatx4*)&Am[c][0]  = *(const floatx4*)(rm1 + om4);
        *(floatx4*)&Am[c][4]  = *(const floatx4*)(rm1 + y0);
        *(floatx4*)&Am[c][8]  = *(const floatx4*)(rm1 + op4);
        *(floatx4*)&C0[c][0]  = *(const floatx4*)(r0 + om4);
        *(floatx4*)&C0[c][4]  = *(const floatx4*)(r0 + y0);
        *(floatx4*)&C0[c][8]  = *(const floatx4*)(r0 + op4);
        *(floatx4*)&C1[c][0]  = *(const floatx4*)(r1 + om4);
        *(floatx4*)&C1[c][4]  = *(const floatx4*)(r1 + y0);
        *(floatx4*)&C1[c][8]  = *(const floatx4*)(r1 + op4);
        *(floatx4*)&Bp[c][0]  = *(const floatx4*)(rp2 + om4);
        *(floatx4*)&Bp[c][4]  = *(const floatx4*)(rp2 + y0);
        *(floatx4*)&Bp[c][8]  = *(const floatx4*)(rp2 + op4);
        *(floatx4*)&B2p[c][0] = *(const floatx4*)(rp3 + y0);
    }

    const float coeff = 2.0f * t[0] * c0[0];

    // b fields, computed once and shared between the two output rows.
    // b0[j] = b(x,   y0-1+j), j=0..5 ; b1[j] = b(x+1, y0-1+j)
    // bm[i] = b(x-1, y0+i)   ; bp2[i] = b(x+2, y0+i)
    float b0[6], b1[6], bm[4], bp2[4];

    #pragma unroll
    for (int j = 0; j < 6; ++j) {
        float a0 = 0.f, a1 = 0.f;
        #pragma unroll
        for (int c = 0; c < 3; ++c) {
            a0 += C0[c][3 + j] * (Am[c][3 + j] + C1[c][3 + j] + C0[c][2 + j] + C0[c][4 + j]);
            a1 += C1[c][3 + j] * (C0[c][3 + j] + Bp[c][3 + j] + C1[c][2 + j] + C1[c][4 + j]);
        }
        b0[j] = a0;
        b1[j] = a1;
    }
    #pragma unroll
    for (int i = 0; i < 4; ++i) {
        float am = 0.f, ap = 0.f;
        #pragma unroll
        for (int c = 0; c < 3; ++c) {
            am += Am[c][4 + i] * (A2m[c][i] + C0[c][4 + i] + Am[c][3 + i] + Am[c][5 + i]);
            ap += Bp[c][4 + i] * (C1[c][4 + i] + B2p[c][i] + Bp[c][3 + i] + Bp[c][5 + i]);
        }
        bm[i]  = am;
        bp2[i] = ap;
    }

    float o0[3][4], o1[3][4];
    #pragma unroll
    for (int i = 0; i < 4; ++i) {
        float G0[3], G1[3];
        #pragma unroll
        for (int c = 0; c < 3; ++c) {
            // output row x: center C0
            float Fs0 = Am[c][4 + i] + C1[c][4 + i] + C0[c][3 + i] + C0[c][5 + i];
            G0[c] = Fs0 * b0[1 + i]
                  + Am[c][4 + i] * bm[i]
                  + C1[c][4 + i] * b1[1 + i]
                  + C0[c][3 + i] * b0[i]
                  + C0[c][5 + i] * b0[2 + i];
            // output row x+1: center C1
            float Fs1 = C0[c][4 + i] + Bp[c][4 + i] + C1[c][3 + i] + C1[c][5 + i];
            G1[c] = Fs1 * b1[1 + i]
                  + C0[c][4 + i] * b0[1 + i]
                  + Bp[c][4 + i] * bp2[i]
                  + C1[c][3 + i] * b1[i]
                  + C1[c][5 + i] * b1[2 + i];
        }
        o0[0][i] = (C0[1][4 + i] * G0[2] - C0[2][4 + i] * G0[1]) * coeff;
        o0[1][i] = (C0[2][4 + i] * G0[0] - C0[0][4 + i] * G0[2]) * coeff;
        o0[2][i] = (C0[0][4 + i] * G0[1] - C0[1][4 + i] * G0[0]) * coeff;
        o1[0][i] = (C1[1][4 + i] * G1[2] - C1[2][4 + i] * G1[1]) * coeff;
        o1[1][i] = (C1[2][4 + i] * G1[0] - C1[0][4 + i] * G1[2]) * coeff;
        o1[2][i] = (C1[0][4 + i] * G1[1] - C1[1][4 + i] * G1[0]) * coeff;
    }

    float* ob = out + (size_t)bidx * 3 * XY + (size_t)x * NY + y0;
    #pragma unroll
    for (int c = 0; c < 3; ++c) {
        floatx4 v0 = { o0[c][0], o0[c][1], o0[c][2], o0[c][3] };
        floatx4 v1 = { o1[c][0], o1[c][1], o1[c][2], o1[c][3] };
        __builtin_nontemporal_store(v0, (floatx4*)(ob + (size_t)c * XY));
        __builtin_nontemporal_store(v1, (floatx4*)(ob + (size_t)c * XY + NY));
    }
}

extern "C" void kernel_launch(void* const* d_in, const int* in_sizes, int n_in,
                              void* d_out, int out_size, void* d_ws, size_t ws_size,
                              hipStream_t stream) {
    const float* s  = (const float*)d_in[0];
    const float* t  = (const float*)d_in[1];
    const float* c0 = (const float*)d_in[2];
    float* out = (float*)d_out;

    psi11t_kernel<<<4096, 256, 0, stream>>>(s, t, c0, out);
}

// Round 7
// 192.651 us; speedup vs baseline: 1.0895x; 1.0058x over previous
//
#include <hip/hip_runtime.h>

#define BATCH 32
#define NX 512
#define NY 512
#define XY (NX * NY)

typedef float floatx4 __attribute__((ext_vector_type(4)));

// __launch_bounds__(256, 2): cap at 2 blocks/CU -> up to 256 VGPRs/thread, so
// all 42 stencil loads can be live at once (one vmcnt round, max MLP).
__global__ __launch_bounds__(256, 2) void psi11t_kernel(
    const float* __restrict__ s,
    const float* __restrict__ t,
    const float* __restrict__ c0,
    float* __restrict__ out)
{
    // XCD swizzle: each XCD (D%8) gets 512 consecutive logical blocks = 4 whole
    // batches -> all halo reuse (incl. x-wrap) stays within one XCD's L2.
    const int D = blockIdx.x;                 // 4096 blocks
    const int L = (D & 7) * 512 + (D >> 3);
    const int bidx  = L >> 7;                 // 32 batches
    const int strip = L & 127;                // 128 strips of 4 rows

    const int tid = threadIdx.x;
    const int yg  = tid & 127;                // 128 y-groups of 4
    const int xr  = tid >> 7;                 // 0/1: which row-pair
    const int y0  = yg * 4;
    const int x   = strip * 4 + xr * 2;       // outputs at rows x, x+1 (x even)

    const int xm2 = (x + NX - 2) & (NX - 1);
    const int xm1 = (x + NX - 1) & (NX - 1);
    const int xp1 = x + 1;                    // x even, <= 510 -> no wrap
    const int xp2 = (x + 2) & (NX - 1);
    const int xp3 = (x + 3) & (NX - 1);
    const int om4 = (y0 + NY - 4) & (NY - 1);
    const int op4 = (y0 + 4)      & (NY - 1);

    const float* sb = s + (size_t)bidx * 3 * XY;

    // Row windows. Index w <-> y = y0 - 4 + w (12-wide rows); A2m/B2p start at y0.
    float A2m[3][4], Am[3][12], C0[3][12], C1[3][12], Bp[3][12], B2p[3][4];

    #pragma unroll
    for (int c = 0; c < 3; ++c) {
        const float* base = sb + (size_t)c * XY;
        const float* rm2 = base + (size_t)xm2 * NY;
        const float* rm1 = base + (size_t)xm1 * NY;
        const float* r0  = base + (size_t)x   * NY;
        const float* r1  = base + (size_t)xp1 * NY;
        const float* rp2 = base + (size_t)xp2 * NY;
        const float* rp3 = base + (size_t)xp3 * NY;

        *(floatx4*)&A2m[c][0] = *(const floatx4*)(rm2 + y0);
        *(floatx4*)&Am[c][0]  = *(const floatx4*)(rm1 + om4);
        *(floatx4*)&Am[c][4]  = *(const floatx4*)(rm1 + y0);
        *(floatx4*)&Am[c][8]  = *(const floatx4*)(rm1 + op4);
        *(floatx4*)&C0[c][0]  = *(const floatx4*)(r0 + om4);
        *(floatx4*)&C0[c][4]  = *(const floatx4*)(r0 + y0);
        *(floatx4*)&C0[c][8]  = *(const floatx4*)(r0 + op4);
        *(floatx4*)&C1[c][0]  = *(const floatx4*)(r1 + om4);
        *(floatx4*)&C1[c][4]  = *(const floatx4*)(r1 + y0);
        *(floatx4*)&C1[c][8]  = *(const floatx4*)(r1 + op4);
        *(floatx4*)&Bp[c][0]  = *(const floatx4*)(rp2 + om4);
        *(floatx4*)&Bp[c][4]  = *(const floatx4*)(rp2 + y0);
        *(floatx4*)&Bp[c][8]  = *(const floatx4*)(rp2 + op4);
        *(floatx4*)&B2p[c][0] = *(const floatx4*)(rp3 + y0);
    }

    const float coeff = 2.0f * t[0] * c0[0];

    // b fields, computed once and shared between the two output rows.
    // b0[j] = b(x,   y0-1+j), j=0..5 ; b1[j] = b(x+1, y0-1+j)
    // bm[i] = b(x-1, y0+i)   ; bp2[i] = b(x+2, y0+i)
    float b0[6], b1[6], bm[4], bp2[4];

    #pragma unroll
    for (int j = 0; j < 6; ++j) {
        float a0 = 0.f, a1 = 0.f;
        #pragma unroll
        for (int c = 0; c < 3; ++c) {
            a0 += C0[c][3 + j] * (Am[c][3 + j] + C1[c][3 + j] + C0[c][2 + j] + C0[c][4 + j]);
            a1 += C1[c][3 + j] * (C0[c][3 + j] + Bp[c][3 + j] + C1[c][2 + j] + C1[c][4 + j]);
        }
        b0[j] = a0;
        b1[j] = a1;
    }
    #pragma unroll
    for (int i = 0; i < 4; ++i) {
        float am = 0.f, ap = 0.f;
        #pragma unroll
        for (int c = 0; c < 3; ++c) {
            am += Am[c][4 + i] * (A2m[c][i] + C0[c][4 + i] + Am[c][3 + i] + Am[c][5 + i]);
            ap += Bp[c][4 + i] * (C1[c][4 + i] + B2p[c][i] + Bp[c][3 + i] + Bp[c][5 + i]);
        }
        bm[i]  = am;
        bp2[i] = ap;
    }

    float o0[3][4], o1[3][4];
    #pragma unroll
    for (int i = 0; i < 4; ++i) {
        float G0[3], G1[3];
        #pragma unroll
        for (int c = 0; c < 3; ++c) {
            // output row x: center C0
            float Fs0 = Am[c][4 + i] + C1[c][4 + i] + C0[c][3 + i] + C0[c][5 + i];
            G0[c] = Fs0 * b0[1 + i]
                  + Am[c][4 + i] * bm[i]
                  + C1[c][4 + i] * b1[1 + i]
                  + C0[c][3 + i] * b0[i]
                  + C0[c][5 + i] * b0[2 + i];
            // output row x+1: center C1
            float Fs1 = C0[c][4 + i] + Bp[c][4 + i] + C1[c][3 + i] + C1[c][5 + i];
            G1[c] = Fs1 * b1[1 + i]
                  + C0[c][4 + i] * b0[1 + i]
                  + Bp[c][4 + i] * bp2[i]
                  + C1[c][3 + i] * b1[i]
                  + C1[c][5 + i] * b1[2 + i];
        }
        o0[0][i] = (C0[1][4 + i] * G0[2] - C0[2][4 + i] * G0[1]) * coeff;
        o0[1][i] = (C0[2][4 + i] * G0[0] - C0[0][4 + i] * G0[2]) * coeff;
        o0[2][i] = (C0[0][4 + i] * G0[1] - C0[1][4 + i] * G0[0]) * coeff;
        o1[0][i] = (C1[1][4 + i] * G1[2] - C1[2][4 + i] * G1[1]) * coeff;
        o1[1][i] = (C1[2][4 + i] * G1[0] - C1[0][4 + i] * G1[2]) * coeff;
        o1[2][i] = (C1[0][4 + i] * G1[1] - C1[1][4 + i] * G1[0]) * coeff;
    }

    float* ob = out + (size_t)bidx * 3 * XY + (size_t)x * NY + y0;
    #pragma unroll
    for (int c = 0; c < 3; ++c) {
        floatx4 v0 = { o0[c][0], o0[c][1], o0[c][2], o0[c][3] };
        floatx4 v1 = { o1[c][0], o1[c][1], o1[c][2], o1[c][3] };
        __builtin_nontemporal_store(v0, (floatx4*)(ob + (size_t)c * XY));
        __builtin_nontemporal_store(v1, (floatx4*)(ob + (size_t)c * XY + NY));
    }
}

extern "C" void kernel_launch(void* const* d_in, const int* in_sizes, int n_in,
                              void* d_out, int out_size, void* d_ws, size_t ws_size,
                              hipStream_t stream) {
    const float* s  = (const float*)d_in[0];
    const float* t  = (const float*)d_in[1];
    const float* c0 = (const float*)d_in[2];
    float* out = (float*)d_out;

    psi11t_kernel<<<4096, 256, 0, stream>>>(s, t, c0, out);
}